// Round 7
// baseline (414.375 us; speedup 1.0000x reference)
//
#include <hip/hip_runtime.h>
#include <math.h>

// Problem constants
#define Bc   4
#define Hc   64
#define Wc   64
#define Dc   384
#define Nc   4096      // H*W
#define Mc   12
#define Pc   9
#define DHc  32
#define DFFc 1152
#define BNc  (Bc*Nc)   // 16384

typedef __attribute__((ext_vector_type(8))) short short8;
typedef __attribute__((ext_vector_type(4))) float floatx4;

__device__ __forceinline__ ushort f2bf(float f) {
    union { float f; unsigned u; } v; v.f = f;
    unsigned r = v.u + 0x7fffu + ((v.u >> 16) & 1u);   // RNE
    return (ushort)(r >> 16);
}

__device__ __forceinline__ void gload_lds16(const void* g, void* l) {
    __builtin_amdgcn_global_load_lds(
        (const __attribute__((address_space(1))) void*)(uintptr_t)g,
        (__attribute__((address_space(3))) void*)(uintptr_t)l,
        16, 0, 0);
}

// ---------------------------------------------------------------------------
// K0: fused init — weight fp32->bf16 convert, bias concat, mask cumsums
// ---------------------------------------------------------------------------
#define SOW_N  82944     // 216*384
#define AWW_N  41472     // 108*384
#define VPW_N  147456    // 384*384
#define OPW_N  147456
#define W1_N   442368    // 1152*384
#define W2_N   442368    // 384*1152
#define WTOT   1304064

__global__ void init_kernel(const float* __restrict__ so_w,
                            const float* __restrict__ aw_w,
                            const float* __restrict__ vp_w,
                            const float* __restrict__ op_w,
                            const float* __restrict__ w1,
                            const float* __restrict__ w2,
                            const float* __restrict__ so_b,
                            const float* __restrict__ aw_b,
                            const float* __restrict__ qmask,
                            ushort* __restrict__ out,
                            float* __restrict__ bias_out,
                            float* __restrict__ cum_y,
                            float* __restrict__ cum_x) {
    int i = blockIdx.x * 256 + threadIdx.x;
    if (i < WTOT) {
        float v;
        int j = i;
        if (j < SOW_N) v = so_w[j];
        else if ((j -= SOW_N) < AWW_N) v = aw_w[j];
        else if ((j -= AWW_N) < VPW_N) v = vp_w[j];
        else if ((j -= VPW_N) < OPW_N) v = op_w[j];
        else if ((j -= OPW_N) < W1_N)  v = w1[j];
        else { j -= W1_N; v = w2[j]; }
        out[i] = f2bf(v);
        return;
    }
    int j = i - WTOT;
    if (j < 384) {   // pad bias to 384 with zeros (col-tile over-read safety)
        bias_out[j] = (j < 216) ? so_b[j] : (j < 324 ? aw_b[j - 216] : 0.f);
        return;
    }
    int t = j - 384;
    if (t < Bc * Wc) {
        int b = t / Wc, w = t % Wc;
        float run = 0.f;
        for (int h = 0; h < Hc; ++h) {
            run += (qmask[(b * Hc + h) * Wc + w] == 255.0f) ? 0.f : 1.f;
            cum_y[(b * Hc + h) * Wc + w] = run;
        }
    } else if (t < Bc * Wc + Bc * Hc) {
        int t2 = t - Bc * Wc;
        int b = t2 / Hc, h = t2 % Hc;
        float run = 0.f;
        for (int w = 0; w < Wc; ++w) {
            run += (qmask[(b * Hc + h) * Wc + w] == 255.0f) ? 0.f : 1.f;
            cum_x[(b * Hc + h) * Wc + w] = run;
        }
    }
}

// ---------------------------------------------------------------------------
// K1: transpose x[B,D,N] -> src_f[B,N,D] (fp32) + src_bf (bf16);
//     qpos_bf = bf16(src + sine_pos + level_embed). Fast-math trig.
// ---------------------------------------------------------------------------
__global__ void transpose_pos_kernel(const float* __restrict__ x,
                                     const float* __restrict__ cum_y,
                                     const float* __restrict__ cum_x,
                                     const float* __restrict__ level_embed,
                                     float* __restrict__ src_f,
                                     ushort* __restrict__ src_bf,
                                     ushort* __restrict__ qpos_bf) {
    __shared__ float tile[32][33];
    int b  = blockIdx.z;
    int n0 = blockIdx.x * 32, d0 = blockIdx.y * 32;
    int tx = threadIdx.x, ty = threadIdx.y;
    tile[ty][tx] = x[((size_t)b * Dc + (d0 + ty)) * Nc + (n0 + tx)];
    __syncthreads();
    int n = n0 + ty, d = d0 + tx;
    float v = tile[tx][ty];
    size_t oi = ((size_t)b * Nc + n) * Dc + d;
    src_f[oi]  = v;
    src_bf[oi] = f2bf(v);
    int h = n >> 6, w = n & 63;
    const float TWO_PI = 6.28318530717958647692f;
    float vy = cum_y[(b * Hc + h) * Wc + w] /
               (cum_y[(b * Hc + (Hc - 1)) * Wc + w] + 1e-6f) * TWO_PI;
    float vx = cum_x[(b * Hc + h) * Wc + w] /
               (cum_x[(b * Hc + h) * Wc + (Wc - 1)] + 1e-6f) * TWO_PI;
    int   i  = (d < 192) ? d : d - 192;
    float vv = (d < 192) ? vy : vx;
    float e   = (float)(i >> 1) * (2.0f / 192.0f);
    float idt = exp2f(e * -13.28771237954945f);
    float ang = vv * idt;
    float pe  = (i & 1) ? __cosf(ang) : __sinf(ang);
    qpos_bf[oi] = f2bf(v + pe + level_embed[d]);
}

// ---------------------------------------------------------------------------
// K2: tall-skinny bf16 MFMA GEMM v7.
//     C[16384, Nout] = A[16384,KT] * Wt[Nout,KT]^T (+bias)(+relu)(+rowmask)
//     Block = 64-row stripe x (NCT*128) cols. A-stripe staged ONCE per
//     384-K chunk into LDS [koct][row][8] (48KB); all columns computed with
//     no further barriers (288 MFMA/wave/chunk). B streams L2->regs: one
//     wave-instruction covers 16 cols x 4 k-octets = 16 fully-used 64B lines.
//     Waves: rg=row-group (2x32 rows), cg=col-group (2x64 cols).
// ---------------------------------------------------------------------------
template <int KT, int NCT>
__global__ __launch_bounds__(256) void gemm_v7_kernel(
        const ushort* __restrict__ A, const ushort* __restrict__ Wt,
        const float* __restrict__ bias,
        float* __restrict__ Cf, ushort* __restrict__ Cb,
        int Nout, int relu, const float* __restrict__ qmask) {
    __shared__ ushort As[48 * 64 * 8];   // 48 k-octets x 64 rows x 8 = 48KB
    const int tid  = threadIdx.x;
    const int lane = tid & 63;
    const int wv   = tid >> 6;
    const int quad = lane >> 4;
    const int lrow = lane & 15;
    const int rg   = wv >> 1;
    const int cg   = wv & 1;
    const int m0   = blockIdx.x * 64;
    const int colbase = blockIdx.y * (NCT * 128);

    floatx4 acc[NCT][2][4];
    #pragma unroll
    for (int ct = 0; ct < NCT; ++ct)
        #pragma unroll
        for (int ri = 0; ri < 2; ++ri)
            #pragma unroll
            for (int j = 0; j < 4; ++j)
                acc[ct][ri][j] = (floatx4)(0.f);

    for (int kc = 0; kc < KT; kc += 384) {
        if (kc) __syncthreads();          // protect As before restage
        // stage A-chunk: wave wv stages k-octets wv*12 .. wv*12+11; lane=row
        {
            const ushort* ga = A + (size_t)(m0 + lane) * KT + kc + wv * 96;
            ushort* la = As + wv * 6144;
            #pragma unroll
            for (int s = 0; s < 12; ++s)
                gload_lds16(ga + s * 8, la + s * 512);
        }
        __syncthreads();

        #pragma unroll
        for (int ks = 0; ks < 12; ++ks) {
            short8 afr[2];
            #pragma unroll
            for (int ri = 0; ri < 2; ++ri)
                afr[ri] = *(const short8*)(As +
                    ((ks * 4 + quad) * 64 + rg * 32 + ri * 16 + lrow) * 8);
            #pragma unroll
            for (int ct = 0; ct < NCT; ++ct) {
                short8 bfr[4];
                #pragma unroll
                for (int j = 0; j < 4; ++j) {
                    int col = colbase + ct * 128 + cg * 64 + j * 16 + lrow;
                    bfr[j] = *(const short8*)(Wt + (size_t)col * KT +
                                              kc + ks * 32 + quad * 8);
                }
                #pragma unroll
                for (int ri = 0; ri < 2; ++ri)
                    #pragma unroll
                    for (int j = 0; j < 4; ++j)
                        acc[ct][ri][j] = __builtin_amdgcn_mfma_f32_16x16x32_bf16(
                            afr[ri], bfr[j], acc[ct][ri][j], 0, 0, 0);
            }
        }
    }

    // row-mask multipliers (value projection only)
    float mz[2][4];
    #pragma unroll
    for (int ri = 0; ri < 2; ++ri)
        #pragma unroll
        for (int r = 0; r < 4; ++r) {
            int row = m0 + rg * 32 + ri * 16 + quad * 4 + r;
            mz[ri][r] = (qmask && qmask[row] == 255.0f) ? 0.f : 1.f;
        }

    // C/D layout (16x16x32): col = lane&15, row = quad*4 + reg
    #pragma unroll
    for (int ct = 0; ct < NCT; ++ct) {
        #pragma unroll
        for (int j = 0; j < 4; ++j) {
            int col = colbase + ct * 128 + cg * 64 + j * 16 + lrow;
            if (col >= Nout) continue;
            float bsv = bias ? bias[col] : 0.f;
            #pragma unroll
            for (int ri = 0; ri < 2; ++ri) {
                #pragma unroll
                for (int r = 0; r < 4; ++r) {
                    int row = m0 + rg * 32 + ri * 16 + quad * 4 + r;
                    float v = acc[ct][ri][j][r] + bsv;
                    if (relu) v = fmaxf(v, 0.f);
                    v *= mz[ri][r];
                    if (Cf) Cf[(size_t)row * Nout + col] = v;
                    if (Cb) Cb[(size_t)row * Nout + col] = f2bf(v);
                }
            }
        }
    }
}

// ---------------------------------------------------------------------------
// K4: deformable attention gather (softmax fused).
//     4-lane group per (b,n,m); lane = 8 channels (bf16x8 = 16B loads).
// ---------------------------------------------------------------------------
__global__ __launch_bounds__(256) void deform_attn_kernel(
        const ushort* __restrict__ value_bf, const float* __restrict__ soaw,
        ushort* __restrict__ out) {
    int gid = blockIdx.x * 64 + (threadIdx.x >> 2);   // (b*N+n)*M + m
    int l4  = threadIdx.x & 3;                        // channel octet
    int m  = gid % Mc;
    int bn = gid / Mc;
    int b  = bn >> 12;
    int n  = bn & 4095;
    int h  = n >> 6, w = n & 63;
    const float* sop = soaw + (size_t)bn * 384 + m * 18;
    const float* lgt = soaw + (size_t)bn * 384 + 216 + m * Pc;
    float awv[Pc];
    float mx = lgt[0];
    #pragma unroll
    for (int i = 1; i < Pc; ++i) mx = fmaxf(mx, lgt[i]);
    float ssum = 0.f;
    #pragma unroll
    for (int i = 0; i < Pc; ++i) { awv[i] = __expf(lgt[i] - mx); ssum += awv[i]; }
    float sinv = 1.f / ssum;
    const ushort* vb = value_bf + ((size_t)b * Nc) * Dc + m * DHc + l4 * 8;
    float acc[8] = {0.f, 0.f, 0.f, 0.f, 0.f, 0.f, 0.f, 0.f};
    #pragma unroll
    for (int p = 0; p < Pc; ++p) {
        float2 so2 = *(const float2*)(sop + p * 2);
        float px = (float)w + so2.x;     // (ref + so/64)*64 - 0.5 simplifies
        float py = (float)h + so2.y;
        float x0f = floorf(px), y0f = floorf(py);
        float lx = px - x0f, ly = py - y0f;
        int x0 = (int)x0f, y0 = (int)y0f;
        int x1 = x0 + 1,  y1 = y0 + 1;
        float a = awv[p] * sinv;
        float w00 = (1.f - lx) * (1.f - ly) * a;
        float w01 = lx * (1.f - ly) * a;
        float w10 = (1.f - lx) * ly * a;
        float w11 = lx * ly * a;
        bool bx0 = (unsigned)x0 < 64u, bx1 = (unsigned)x1 < 64u;
        bool by0 = (unsigned)y0 < 64u, by1 = (unsigned)y1 < 64u;
        w00 = (bx0 && by0) ? w00 : 0.f;
        w01 = (bx1 && by0) ? w01 : 0.f;
        w10 = (bx0 && by1) ? w10 : 0.f;
        w11 = (bx1 && by1) ? w11 : 0.f;
        int cx0 = min(max(x0, 0), 63), cx1 = min(max(x1, 0), 63);
        int cy0 = min(max(y0, 0), 63), cy1 = min(max(y1, 0), 63);
        uint4 q00 = *(const uint4*)(vb + (size_t)(cy0 * 64 + cx0) * Dc);
        uint4 q01 = *(const uint4*)(vb + (size_t)(cy0 * 64 + cx1) * Dc);
        uint4 q10 = *(const uint4*)(vb + (size_t)(cy1 * 64 + cx0) * Dc);
        uint4 q11 = *(const uint4*)(vb + (size_t)(cy1 * 64 + cx1) * Dc);
        union { unsigned u; float f; } t;
        #define ACC2(word, wg, k)                                   \
            t.u = (word) << 16;         acc[k]     += (wg) * t.f;   \
            t.u = (word) & 0xffff0000u; acc[k + 1] += (wg) * t.f;
        #define ACC8(q, wg) \
            ACC2((q).x, wg, 0) ACC2((q).y, wg, 2) ACC2((q).z, wg, 4) ACC2((q).w, wg, 6)
        ACC8(q00, w00) ACC8(q01, w01) ACC8(q10, w10) ACC8(q11, w11)
        #undef ACC8
        #undef ACC2
    }
    short8 o;
    #pragma unroll
    for (int k = 0; k < 8; ++k) o[k] = (short)f2bf(acc[k]);
    *(short8*)(out + (size_t)bn * Dc + m * DHc + l4 * 8) = o;
}

// ---------------------------------------------------------------------------
// K5: out = LayerNorm(a + r) * g + beta ; optional bf16 copy. In-place safe.
// ---------------------------------------------------------------------------
__global__ __launch_bounds__(128) void ln_residual_kernel(
        const float* a, const float* r,
        const float* g, const float* beta,
        float* out, ushort* outb) {
    int row = blockIdx.x;
    int tid = threadIdx.x;
    float4 v = make_float4(0.f, 0.f, 0.f, 0.f);
    if (tid < 96) {
        float4 av = ((const float4*)(a + (size_t)row * Dc))[tid];
        float4 rv = ((const float4*)(r + (size_t)row * Dc))[tid];
        v.x = av.x + rv.x; v.y = av.y + rv.y;
        v.z = av.z + rv.z; v.w = av.w + rv.w;
    }
    float s1 = v.x + v.y + v.z + v.w;
    float s2 = v.x * v.x + v.y * v.y + v.z * v.z + v.w * v.w;
    __shared__ float sh1[128], sh2[128];
    sh1[tid] = s1; sh2[tid] = s2;
    __syncthreads();
    for (int off = 64; off > 0; off >>= 1) {
        if (tid < off) { sh1[tid] += sh1[tid + off]; sh2[tid] += sh2[tid + off]; }
        __syncthreads();
    }
    float mu  = sh1[0] * (1.0f / Dc);
    float var = sh2[0] * (1.0f / Dc) - mu * mu;
    float rs  = rsqrtf(var + 1e-5f);
    if (tid < 96) {
        float4 gv = ((const float4*)g)[tid];
        float4 bv = ((const float4*)beta)[tid];
        float4 o;
        o.x = (v.x - mu) * rs * gv.x + bv.x;
        o.y = (v.y - mu) * rs * gv.y + bv.y;
        o.z = (v.z - mu) * rs * gv.z + bv.z;
        o.w = (v.w - mu) * rs * gv.w + bv.w;
        ((float4*)(out + (size_t)row * Dc))[tid] = o;
        if (outb) {
            ushort4 ob;
            ob.x = f2bf(o.x); ob.y = f2bf(o.y);
            ob.z = f2bf(o.z); ob.w = f2bf(o.w);
            ((ushort4*)(outb + (size_t)row * Dc))[tid] = ob;
        }
    }
}

// ---------------------------------------------------------------------------
// K6: transpose src[B,N,D] -> out[B,D,N]
// ---------------------------------------------------------------------------
__global__ void transpose_out_kernel(const float* __restrict__ src,
                                     float* __restrict__ out) {
    __shared__ float tile[32][33];
    int b  = blockIdx.z;
    int n0 = blockIdx.x * 32, d0 = blockIdx.y * 32;
    int tx = threadIdx.x, ty = threadIdx.y;
    tile[ty][tx] = src[((size_t)b * Nc + (n0 + ty)) * Dc + (d0 + tx)];
    __syncthreads();
    out[((size_t)b * Dc + (d0 + ty)) * Nc + (n0 + tx)] = tile[tx][ty];
}

// ---------------------------------------------------------------------------
extern "C" void kernel_launch(void* const* d_in, const int* in_sizes, int n_in,
                              void* d_out, int out_size, void* d_ws, size_t ws_size,
                              hipStream_t stream) {
    (void)in_sizes; (void)n_in; (void)out_size; (void)ws_size;
    const float* x      = (const float*)d_in[0];
    const float* qmask  = (const float*)d_in[1];
    const float* so_w   = (const float*)d_in[2];
    const float* so_b   = (const float*)d_in[3];
    const float* aw_w   = (const float*)d_in[4];
    const float* aw_b   = (const float*)d_in[5];
    const float* vp_w   = (const float*)d_in[6];
    const float* vp_b   = (const float*)d_in[7];
    const float* op_w   = (const float*)d_in[8];
    const float* op_b   = (const float*)d_in[9];
    const float* ln1_g  = (const float*)d_in[10];
    const float* ln1_b  = (const float*)d_in[11];
    const float* w1     = (const float*)d_in[12];
    const float* w2     = (const float*)d_in[13];
    const float* ln2_g  = (const float*)d_in[14];
    const float* ln2_b  = (const float*)d_in[15];
    const float* lvl    = (const float*)d_in[16];
    float* out = (float*)d_out;

    // Workspace layout (~124 MB in floats):
    float*  ws       = (float*)d_ws;
    float*  src_f    = ws;                          // 6291456 f (residual/q1/q2)
    float*  proj_f   = src_f + 6291456;             // 6291456 f (op out, FFN2 out)
    ushort* src_bf   = (ushort*)(proj_f + 6291456); // 6291456 us
    ushort* qpos_bf  = src_bf + 6291456;            // 6291456 us (qpos->attn->q1_bf)
    ushort* value_bf = qpos_bf + 6291456;           // 6291456 us
    ushort* hbuf_bf  = value_bf + 6291456;          // 18874368 us (FFN hidden)
    float*  soaw_f   = (float*)hbuf_bf;             // 6291456 f overlay [BN,384] (dead pre-FFN1)
    ushort* wbuf     = hbuf_bf + 18874368;          // 1304064 us
    float*  soaw_bias= (float*)(wbuf + 1304064);    // 384 f (padded)
    float*  cum_y    = soaw_bias + 384;             // 16384 f
    float*  cum_x    = cum_y + 16384;               // 16384 f

    const ushort* soaw_wb = wbuf;                   // [324,384] (so_w ++ aw_w)
    const ushort* vp_wb = soaw_wb + SOW_N + AWW_N;
    const ushort* op_wb = vp_wb + VPW_N;
    const ushort* w1_b  = op_wb + OPW_N;
    const ushort* w2_b  = w1_b + W1_N;

    // 0) fused init: weight convert + bias concat (padded) + mask cumsums
    init_kernel<<<(WTOT + 384 + 512 + 255) / 256, 256, 0, stream>>>(
        so_w, aw_w, vp_w, op_w, w1, w2, so_b, aw_b, qmask,
        wbuf, soaw_bias, cum_y, cum_x);
    // 1) transpose + pos encode
    transpose_pos_kernel<<<dim3(Nc / 32, Dc / 32, Bc), dim3(32, 32), 0, stream>>>(
        x, cum_y, cum_x, lvl, src_f, src_bf, qpos_bf);
    // 2) merged so+aw projection (Nout=324, stored with stride 384 via pad?
    //    -> store at stride 324 would break gather; instead Nout param = 324
    //    but we store into a [BN,384] buffer using Nout=384 addressing with
    //    guarded cols: simplest is to compute as Nout=324 matrix. We instead
    //    treat soaw_f as [BN,384] and pass Nout=384 with zero-padded bias and
    //    weight over-read into vp_wb (cols 324..383 produce garbage that the
    //    gather never reads).
    gemm_v7_kernel<384, 3><<<dim3(BNc / 64, 1), 256, 0, stream>>>(
        qpos_bf, soaw_wb, soaw_bias, soaw_f, nullptr, 384, 0, nullptr);
    gemm_v7_kernel<384, 3><<<dim3(BNc / 64, 1), 256, 0, stream>>>(
        src_bf, vp_wb, vp_b, nullptr, value_bf, Dc, 0, qmask);
    // 3) deformable gather (softmax fused), soaw stride 384
    deform_attn_kernel<<<(BNc * Mc) / 64, 256, 0, stream>>>(
        value_bf, soaw_f, qpos_bf);
    // 4) output projection
    gemm_v7_kernel<384, 3><<<dim3(BNc / 64, 1), 256, 0, stream>>>(
        qpos_bf, op_wb, op_b, proj_f, nullptr, Dc, 0, nullptr);
    // 5) q1 = LN(src + attnproj) — in place, bf16 copy to qpos_bf
    ln_residual_kernel<<<BNc, 128, 0, stream>>>(
        src_f, proj_f, ln1_g, ln1_b, src_f, qpos_bf);
    // 6) FFN
    gemm_v7_kernel<384, 3><<<dim3(BNc / 64, 3), 256, 0, stream>>>(
        qpos_bf, w1_b, nullptr, nullptr, hbuf_bf, DFFc, 1, nullptr);
    gemm_v7_kernel<1152, 3><<<dim3(BNc / 64, 1), 256, 0, stream>>>(
        hbuf_bf, w2_b, nullptr, proj_f, nullptr, Dc, 0, nullptr);
    // 7) q2 = LN(q1 + ffn2) — in place
    ln_residual_kernel<<<BNc, 128, 0, stream>>>(
        src_f, proj_f, ln2_g, ln2_b, src_f, nullptr);
    // 8) transpose to [B,D,H,W]
    transpose_out_kernel<<<dim3(Nc / 32, Dc / 32, Bc), dim3(32, 32), 0, stream>>>(
        src_f, out);
}

// Round 8
// 299.172 us; speedup vs baseline: 1.3851x; 1.3851x over previous
//
#include <hip/hip_runtime.h>
#include <math.h>

// Problem constants
#define Bc   4
#define Hc   64
#define Wc   64
#define Dc   384
#define Nc   4096      // H*W
#define Mc   12
#define Pc   9
#define DHc  32
#define DFFc 1152
#define BNc  (Bc*Nc)   // 16384

typedef __attribute__((ext_vector_type(8))) short short8;
typedef __attribute__((ext_vector_type(4))) float floatx4;

__device__ __forceinline__ ushort f2bf(float f) {
    union { float f; unsigned u; } v; v.f = f;
    unsigned r = v.u + 0x7fffu + ((v.u >> 16) & 1u);   // RNE
    return (ushort)(r >> 16);
}

__device__ __forceinline__ void gload_lds16(const void* g, void* l) {
    __builtin_amdgcn_global_load_lds(
        (const __attribute__((address_space(1))) void*)(uintptr_t)g,
        (__attribute__((address_space(3))) void*)(uintptr_t)l,
        16, 0, 0);
}

// ---------------------------------------------------------------------------
// K0: fused init — weight fp32->bf16 convert, bias concat, mask cumsums
// ---------------------------------------------------------------------------
#define SOW_N  82944     // 216*384
#define AWW_N  41472     // 108*384
#define VPW_N  147456    // 384*384
#define OPW_N  147456
#define W1_N   442368    // 1152*384
#define W2_N   442368    // 384*1152
#define WTOT   1304064

__global__ void init_kernel(const float* __restrict__ so_w,
                            const float* __restrict__ aw_w,
                            const float* __restrict__ vp_w,
                            const float* __restrict__ op_w,
                            const float* __restrict__ w1,
                            const float* __restrict__ w2,
                            const float* __restrict__ so_b,
                            const float* __restrict__ aw_b,
                            const float* __restrict__ qmask,
                            ushort* __restrict__ out,
                            float* __restrict__ bias_out,
                            float* __restrict__ cum_y,
                            float* __restrict__ cum_x) {
    int i = blockIdx.x * 256 + threadIdx.x;
    if (i < WTOT) {
        float v;
        int j = i;
        if (j < SOW_N) v = so_w[j];
        else if ((j -= SOW_N) < AWW_N) v = aw_w[j];
        else if ((j -= AWW_N) < VPW_N) v = vp_w[j];
        else if ((j -= VPW_N) < OPW_N) v = op_w[j];
        else if ((j -= OPW_N) < W1_N)  v = w1[j];
        else { j -= W1_N; v = w2[j]; }
        out[i] = f2bf(v);
        return;
    }
    int j = i - WTOT;
    if (j < 384) {   // pad bias to 384 with zeros (col-tile over-read safety)
        bias_out[j] = (j < 216) ? so_b[j] : (j < 324 ? aw_b[j - 216] : 0.f);
        return;
    }
    int t = j - 384;
    if (t < Bc * Wc) {
        int b = t / Wc, w = t % Wc;
        float run = 0.f;
        for (int h = 0; h < Hc; ++h) {
            run += (qmask[(b * Hc + h) * Wc + w] == 255.0f) ? 0.f : 1.f;
            cum_y[(b * Hc + h) * Wc + w] = run;
        }
    } else if (t < Bc * Wc + Bc * Hc) {
        int t2 = t - Bc * Wc;
        int b = t2 / Hc, h = t2 % Hc;
        float run = 0.f;
        for (int w = 0; w < Wc; ++w) {
            run += (qmask[(b * Hc + h) * Wc + w] == 255.0f) ? 0.f : 1.f;
            cum_x[(b * Hc + h) * Wc + w] = run;
        }
    }
}

// ---------------------------------------------------------------------------
// K1: transpose x[B,D,N] -> src_f[B,N,D] (fp32) + src_bf (bf16);
//     qpos_bf = bf16(src + sine_pos + level_embed). Fast-math trig.
// ---------------------------------------------------------------------------
__global__ void transpose_pos_kernel(const float* __restrict__ x,
                                     const float* __restrict__ cum_y,
                                     const float* __restrict__ cum_x,
                                     const float* __restrict__ level_embed,
                                     float* __restrict__ src_f,
                                     ushort* __restrict__ src_bf,
                                     ushort* __restrict__ qpos_bf) {
    __shared__ float tile[32][33];
    int b  = blockIdx.z;
    int n0 = blockIdx.x * 32, d0 = blockIdx.y * 32;
    int tx = threadIdx.x, ty = threadIdx.y;
    tile[ty][tx] = x[((size_t)b * Dc + (d0 + ty)) * Nc + (n0 + tx)];
    __syncthreads();
    int n = n0 + ty, d = d0 + tx;
    float v = tile[tx][ty];
    size_t oi = ((size_t)b * Nc + n) * Dc + d;
    src_f[oi]  = v;
    src_bf[oi] = f2bf(v);
    int h = n >> 6, w = n & 63;
    const float TWO_PI = 6.28318530717958647692f;
    float vy = cum_y[(b * Hc + h) * Wc + w] /
               (cum_y[(b * Hc + (Hc - 1)) * Wc + w] + 1e-6f) * TWO_PI;
    float vx = cum_x[(b * Hc + h) * Wc + w] /
               (cum_x[(b * Hc + h) * Wc + (Wc - 1)] + 1e-6f) * TWO_PI;
    int   i  = (d < 192) ? d : d - 192;
    float vv = (d < 192) ? vy : vx;
    float e   = (float)(i >> 1) * (2.0f / 192.0f);
    float idt = exp2f(e * -13.28771237954945f);
    float ang = vv * idt;
    float pe  = (i & 1) ? __cosf(ang) : __sinf(ang);
    qpos_bf[oi] = f2bf(v + pe + level_embed[d]);
}

// ---------------------------------------------------------------------------
// K2: bf16 MFMA GEMM v8 = R4 (m97-style 128x128, global_load_lds width=16)
//     + XCD grid swizzle (blockIdx.x = row-stripe, fast-varying: all
//       col-tiles of a stripe share linear%8 -> same XCD L2)
//     + double-buffered LDS, ONE barrier per K-chunk (stage c+1 before
//       computing chunk c; the barrier's vmcnt drain overlaps the MFMAs).
// ---------------------------------------------------------------------------
template <int KT>
__global__ __launch_bounds__(256) void gemm_v8_kernel(
        const ushort* __restrict__ A, const ushort* __restrict__ Wt,
        const float* __restrict__ bias,
        float* __restrict__ Cf, ushort* __restrict__ Cb,
        int Nout, int relu, const float* __restrict__ qmask) {
    constexpr int NCH = KT / 32;
    __shared__ ushort As[2][128 * 32];
    __shared__ ushort Bs[2][128 * 32];
    const int tid  = threadIdx.x;
    const int m0   = blockIdx.x * 128;   // row fast-varying -> XCD locality
    const int n0   = blockIdx.y * 128;
    const int lane = tid & 63;
    const int wv   = tid >> 6;
    const int wr   = (wv >> 1) * 64;
    const int wc   = (wv & 1) * 64;
    const int quad = lane >> 4;
    const int lrow = lane & 15;
    // staging: wave wv covers tile rows [wv*32, wv*32+32); inst s: +s*16
    const int srow = wv * 32 + (lane >> 2);
    const int scol = (lane & 3) * 8;

    floatx4 acc[4][4];
    #pragma unroll
    for (int i = 0; i < 4; ++i)
        #pragma unroll
        for (int j = 0; j < 4; ++j)
            acc[i][j] = (floatx4)(0.f);

    // stage chunk 0 into buf 0
    #pragma unroll
    for (int s = 0; s < 2; ++s) {
        gload_lds16(A  + (size_t)(m0 + srow + s * 16) * KT + scol,
                    &As[0][wv * 1024 + s * 512]);
        gload_lds16(Wt + (size_t)(n0 + srow + s * 16) * KT + scol,
                    &Bs[0][wv * 1024 + s * 512]);
    }

    for (int c = 0; c < NCH; ++c) {
        const int cur = c & 1;
        __syncthreads();   // buf[cur] ready (vmcnt drain covered by prev MFMAs)
        if (c + 1 < NCH) {
            const int k0 = (c + 1) * 32;
            #pragma unroll
            for (int s = 0; s < 2; ++s) {
                gload_lds16(A  + (size_t)(m0 + srow + s * 16) * KT + k0 + scol,
                            &As[cur ^ 1][wv * 1024 + s * 512]);
                gload_lds16(Wt + (size_t)(n0 + srow + s * 16) * KT + k0 + scol,
                            &Bs[cur ^ 1][wv * 1024 + s * 512]);
            }
        }
        short8 afr[4], bfr[4];
        #pragma unroll
        for (int i = 0; i < 4; ++i)
            afr[i] = *(const short8*)(&As[cur][(wr + i * 16 + lrow) * 32 + quad * 8]);
        #pragma unroll
        for (int j = 0; j < 4; ++j)
            bfr[j] = *(const short8*)(&Bs[cur][(wc + j * 16 + lrow) * 32 + quad * 8]);
        #pragma unroll
        for (int i = 0; i < 4; ++i)
            #pragma unroll
            for (int j = 0; j < 4; ++j)
                acc[i][j] = __builtin_amdgcn_mfma_f32_16x16x32_bf16(
                    afr[i], bfr[j], acc[i][j], 0, 0, 0);
    }

    // row-mask multipliers (value projection only)
    float mz[4][4];
    #pragma unroll
    for (int i = 0; i < 4; ++i)
        #pragma unroll
        for (int r = 0; r < 4; ++r) {
            int row = m0 + wr + i * 16 + quad * 4 + r;
            mz[i][r] = (qmask && qmask[row] == 255.0f) ? 0.f : 1.f;
        }

    // C/D layout (16x16x32): col = lane&15, row = quad*4 + reg
    #pragma unroll
    for (int i = 0; i < 4; ++i) {
        #pragma unroll
        for (int j = 0; j < 4; ++j) {
            int col = n0 + wc + j * 16 + lrow;
            if (col >= Nout) continue;
            float bsv = bias ? bias[col] : 0.f;
            #pragma unroll
            for (int r = 0; r < 4; ++r) {
                int row = m0 + wr + i * 16 + quad * 4 + r;
                float v = acc[i][j][r] + bsv;
                if (relu) v = fmaxf(v, 0.f);
                v *= mz[i][r];
                if (Cf) Cf[(size_t)row * Nout + col] = v;
                if (Cb) Cb[(size_t)row * Nout + col] = f2bf(v);
            }
        }
    }
}

// ---------------------------------------------------------------------------
// K4: deformable attention gather (softmax fused).
//     4-lane group per (b,n,m); lane = 8 channels (bf16x8 = 16B loads).
//     soaw layout: [BN, 384] (216 offsets | 108 logits | 60 pad).
// ---------------------------------------------------------------------------
__global__ __launch_bounds__(256) void deform_attn_kernel(
        const ushort* __restrict__ value_bf, const float* __restrict__ soaw,
        ushort* __restrict__ out) {
    int gid = blockIdx.x * 64 + (threadIdx.x >> 2);   // (b*N+n)*M + m
    int l4  = threadIdx.x & 3;                        // channel octet
    int m  = gid % Mc;
    int bn = gid / Mc;
    int b  = bn >> 12;
    int n  = bn & 4095;
    int h  = n >> 6, w = n & 63;
    const float* sop = soaw + (size_t)bn * 384 + m * 18;
    const float* lgt = soaw + (size_t)bn * 384 + 216 + m * Pc;
    float awv[Pc];
    float mx = lgt[0];
    #pragma unroll
    for (int i = 1; i < Pc; ++i) mx = fmaxf(mx, lgt[i]);
    float ssum = 0.f;
    #pragma unroll
    for (int i = 0; i < Pc; ++i) { awv[i] = __expf(lgt[i] - mx); ssum += awv[i]; }
    float sinv = 1.f / ssum;
    const ushort* vb = value_bf + ((size_t)b * Nc) * Dc + m * DHc + l4 * 8;
    float acc[8] = {0.f, 0.f, 0.f, 0.f, 0.f, 0.f, 0.f, 0.f};
    #pragma unroll
    for (int p = 0; p < Pc; ++p) {
        float2 so2 = *(const float2*)(sop + p * 2);
        float px = (float)w + so2.x;     // (ref + so/64)*64 - 0.5 simplifies
        float py = (float)h + so2.y;
        float x0f = floorf(px), y0f = floorf(py);
        float lx = px - x0f, ly = py - y0f;
        int x0 = (int)x0f, y0 = (int)y0f;
        int x1 = x0 + 1,  y1 = y0 + 1;
        float a = awv[p] * sinv;
        float w00 = (1.f - lx) * (1.f - ly) * a;
        float w01 = lx * (1.f - ly) * a;
        float w10 = (1.f - lx) * ly * a;
        float w11 = lx * ly * a;
        bool bx0 = (unsigned)x0 < 64u, bx1 = (unsigned)x1 < 64u;
        bool by0 = (unsigned)y0 < 64u, by1 = (unsigned)y1 < 64u;
        w00 = (bx0 && by0) ? w00 : 0.f;
        w01 = (bx1 && by0) ? w01 : 0.f;
        w10 = (bx0 && by1) ? w10 : 0.f;
        w11 = (bx1 && by1) ? w11 : 0.f;
        int cx0 = min(max(x0, 0), 63), cx1 = min(max(x1, 0), 63);
        int cy0 = min(max(y0, 0), 63), cy1 = min(max(y1, 0), 63);
        uint4 q00 = *(const uint4*)(vb + (size_t)(cy0 * 64 + cx0) * Dc);
        uint4 q01 = *(const uint4*)(vb + (size_t)(cy0 * 64 + cx1) * Dc);
        uint4 q10 = *(const uint4*)(vb + (size_t)(cy1 * 64 + cx0) * Dc);
        uint4 q11 = *(const uint4*)(vb + (size_t)(cy1 * 64 + cx1) * Dc);
        union { unsigned u; float f; } t;
        #define ACC2(word, wg, k)                                   \
            t.u = (word) << 16;         acc[k]     += (wg) * t.f;   \
            t.u = (word) & 0xffff0000u; acc[k + 1] += (wg) * t.f;
        #define ACC8(q, wg) \
            ACC2((q).x, wg, 0) ACC2((q).y, wg, 2) ACC2((q).z, wg, 4) ACC2((q).w, wg, 6)
        ACC8(q00, w00) ACC8(q01, w01) ACC8(q10, w10) ACC8(q11, w11)
        #undef ACC8
        #undef ACC2
    }
    short8 o;
    #pragma unroll
    for (int k = 0; k < 8; ++k) o[k] = (short)f2bf(acc[k]);
    *(short8*)(out + (size_t)bn * Dc + m * DHc + l4 * 8) = o;
}

// ---------------------------------------------------------------------------
// K5: out = LayerNorm(a + r) * g + beta ; optional bf16 copy. In-place safe.
// ---------------------------------------------------------------------------
__global__ __launch_bounds__(128) void ln_residual_kernel(
        const float* a, const float* r,
        const float* g, const float* beta,
        float* out, ushort* outb) {
    int row = blockIdx.x;
    int tid = threadIdx.x;
    float4 v = make_float4(0.f, 0.f, 0.f, 0.f);
    if (tid < 96) {
        float4 av = ((const float4*)(a + (size_t)row * Dc))[tid];
        float4 rv = ((const float4*)(r + (size_t)row * Dc))[tid];
        v.x = av.x + rv.x; v.y = av.y + rv.y;
        v.z = av.z + rv.z; v.w = av.w + rv.w;
    }
    float s1 = v.x + v.y + v.z + v.w;
    float s2 = v.x * v.x + v.y * v.y + v.z * v.z + v.w * v.w;
    __shared__ float sh1[128], sh2[128];
    sh1[tid] = s1; sh2[tid] = s2;
    __syncthreads();
    for (int off = 64; off > 0; off >>= 1) {
        if (tid < off) { sh1[tid] += sh1[tid + off]; sh2[tid] += sh2[tid + off]; }
        __syncthreads();
    }
    float mu  = sh1[0] * (1.0f / Dc);
    float var = sh2[0] * (1.0f / Dc) - mu * mu;
    float rs  = rsqrtf(var + 1e-5f);
    if (tid < 96) {
        float4 gv = ((const float4*)g)[tid];
        float4 bv = ((const float4*)beta)[tid];
        float4 o;
        o.x = (v.x - mu) * rs * gv.x + bv.x;
        o.y = (v.y - mu) * rs * gv.y + bv.y;
        o.z = (v.z - mu) * rs * gv.z + bv.z;
        o.w = (v.w - mu) * rs * gv.w + bv.w;
        ((float4*)(out + (size_t)row * Dc))[tid] = o;
        if (outb) {
            ushort4 ob;
            ob.x = f2bf(o.x); ob.y = f2bf(o.y);
            ob.z = f2bf(o.z); ob.w = f2bf(o.w);
            ((ushort4*)(outb + (size_t)row * Dc))[tid] = ob;
        }
    }
}

// ---------------------------------------------------------------------------
// K6: transpose src[B,N,D] -> out[B,D,N]
// ---------------------------------------------------------------------------
__global__ void transpose_out_kernel(const float* __restrict__ src,
                                     float* __restrict__ out) {
    __shared__ float tile[32][33];
    int b  = blockIdx.z;
    int n0 = blockIdx.x * 32, d0 = blockIdx.y * 32;
    int tx = threadIdx.x, ty = threadIdx.y;
    tile[ty][tx] = src[((size_t)b * Nc + (n0 + ty)) * Dc + (d0 + tx)];
    __syncthreads();
    out[((size_t)b * Dc + (d0 + ty)) * Nc + (n0 + tx)] = tile[tx][ty];
}

// ---------------------------------------------------------------------------
extern "C" void kernel_launch(void* const* d_in, const int* in_sizes, int n_in,
                              void* d_out, int out_size, void* d_ws, size_t ws_size,
                              hipStream_t stream) {
    (void)in_sizes; (void)n_in; (void)out_size; (void)ws_size;
    const float* x      = (const float*)d_in[0];
    const float* qmask  = (const float*)d_in[1];
    const float* so_w   = (const float*)d_in[2];
    const float* so_b   = (const float*)d_in[3];
    const float* aw_w   = (const float*)d_in[4];
    const float* aw_b   = (const float*)d_in[5];
    const float* vp_w   = (const float*)d_in[6];
    const float* vp_b   = (const float*)d_in[7];
    const float* op_w   = (const float*)d_in[8];
    const float* op_b   = (const float*)d_in[9];
    const float* ln1_g  = (const float*)d_in[10];
    const float* ln1_b  = (const float*)d_in[11];
    const float* w1     = (const float*)d_in[12];
    const float* w2     = (const float*)d_in[13];
    const float* ln2_g  = (const float*)d_in[14];
    const float* ln2_b  = (const float*)d_in[15];
    const float* lvl    = (const float*)d_in[16];
    float* out = (float*)d_out;

    // Workspace layout (~124 MB in floats):
    float*  ws       = (float*)d_ws;
    float*  src_f    = ws;                          // 6291456 f (residual/q1/q2)
    float*  proj_f   = src_f + 6291456;             // 6291456 f (op out, FFN2 out)
    ushort* src_bf   = (ushort*)(proj_f + 6291456); // 6291456 us
    ushort* qpos_bf  = src_bf + 6291456;            // 6291456 us (qpos->attn->q1_bf)
    ushort* value_bf = qpos_bf + 6291456;           // 6291456 us
    ushort* hbuf_bf  = value_bf + 6291456;          // 18874368 us (FFN hidden)
    float*  soaw_f   = (float*)hbuf_bf;             // 6291456 f overlay [BN,384] (dead pre-FFN1)
    ushort* wbuf     = hbuf_bf + 18874368;          // 1304064 us
    float*  soaw_bias= (float*)(wbuf + 1304064);    // 384 f (padded)
    float*  cum_y    = soaw_bias + 384;             // 16384 f
    float*  cum_x    = cum_y + 16384;               // 16384 f

    const ushort* soaw_wb = wbuf;                   // [324,384] (so_w ++ aw_w)
    const ushort* vp_wb = soaw_wb + SOW_N + AWW_N;
    const ushort* op_wb = vp_wb + VPW_N;
    const ushort* w1_b  = op_wb + OPW_N;
    const ushort* w2_b  = w1_b + W1_N;

    // 0) fused init: weight convert + bias concat (padded) + mask cumsums
    init_kernel<<<(WTOT + 384 + 512 + 255) / 256, 256, 0, stream>>>(
        so_w, aw_w, vp_w, op_w, w1, w2, so_b, aw_b, qmask,
        wbuf, soaw_bias, cum_y, cum_x);
    // 1) transpose + pos encode
    transpose_pos_kernel<<<dim3(Nc / 32, Dc / 32, Bc), dim3(32, 32), 0, stream>>>(
        x, cum_y, cum_x, lvl, src_f, src_bf, qpos_bf);
    // 2) merged so+aw projection ([BN,384] layout; cols 324..383 are benign
    //    garbage from over-read weights, never read by the gather), then
    //    value projection. Grid: (rows, cols) for XCD L2 locality.
    gemm_v8_kernel<384><<<dim3(BNc / 128, 3), 256, 0, stream>>>(
        qpos_bf, soaw_wb, soaw_bias, soaw_f, nullptr, 384, 0, nullptr);
    gemm_v8_kernel<384><<<dim3(BNc / 128, 3), 256, 0, stream>>>(
        src_bf, vp_wb, vp_b, nullptr, value_bf, Dc, 0, qmask);
    // 3) deformable gather (softmax fused) -> attn_bf (into qpos_bf; qpos dead)
    deform_attn_kernel<<<(BNc * Mc) / 64, 256, 0, stream>>>(
        value_bf, soaw_f, qpos_bf);
    // 4) output projection
    gemm_v8_kernel<384><<<dim3(BNc / 128, 3), 256, 0, stream>>>(
        qpos_bf, op_wb, op_b, proj_f, nullptr, Dc, 0, nullptr);
    // 5) q1 = LN(src + attnproj) — in place, bf16 copy to qpos_bf
    ln_residual_kernel<<<BNc, 128, 0, stream>>>(
        src_f, proj_f, ln1_g, ln1_b, src_f, qpos_bf);
    // 6) FFN
    gemm_v8_kernel<384><<<dim3(BNc / 128, 9), 256, 0, stream>>>(
        qpos_bf, w1_b, nullptr, nullptr, hbuf_bf, DFFc, 1, nullptr);
    gemm_v8_kernel<1152><<<dim3(BNc / 128, 3), 256, 0, stream>>>(
        hbuf_bf, w2_b, nullptr, proj_f, nullptr, Dc, 0, nullptr);
    // 7) q2 = LN(q1 + ffn2) — in place
    ln_residual_kernel<<<BNc, 128, 0, stream>>>(
        src_f, proj_f, ln2_g, ln2_b, src_f, nullptr);
    // 8) transpose to [B,D,H,W]
    transpose_out_kernel<<<dim3(Nc / 32, Dc / 32, Bc), dim3(32, 32), 0, stream>>>(
        src_f, out);
}

// Round 9
// 271.893 us; speedup vs baseline: 1.5240x; 1.1003x over previous
//
#include <hip/hip_runtime.h>
#include <math.h>

// Problem constants
#define Bc   4
#define Hc   64
#define Wc   64
#define Dc   384
#define Nc   4096      // H*W
#define Mc   12
#define Pc   9
#define DHc  32
#define DFFc 1152
#define BNc  (Bc*Nc)   // 16384

typedef __attribute__((ext_vector_type(8))) short short8;
typedef __attribute__((ext_vector_type(4))) float floatx4;

__device__ __forceinline__ ushort f2bf(float f) {
    union { float f; unsigned u; } v; v.f = f;
    unsigned r = v.u + 0x7fffu + ((v.u >> 16) & 1u);   // RNE
    return (ushort)(r >> 16);
}
__device__ __forceinline__ float bf2f(ushort u) {
    union { unsigned u; float f; } v; v.u = (unsigned)u << 16; return v.f;
}

__device__ __forceinline__ void gload_lds16(const void* g, void* l) {
    __builtin_amdgcn_global_load_lds(
        (const __attribute__((address_space(1))) void*)(uintptr_t)g,
        (__attribute__((address_space(3))) void*)(uintptr_t)l,
        16, 0, 0);
}

// ---------------------------------------------------------------------------
// K0: fused init — weight fp32->bf16 convert, bias concat, mask cumsums
// ---------------------------------------------------------------------------
#define SOW_N  82944     // 216*384
#define AWW_N  41472     // 108*384
#define VPW_N  147456    // 384*384
#define OPW_N  147456
#define W1_N   442368    // 1152*384
#define W2_N   442368    // 384*1152
#define WTOT   1304064

__global__ void init_kernel(const float* __restrict__ so_w,
                            const float* __restrict__ aw_w,
                            const float* __restrict__ vp_w,
                            const float* __restrict__ op_w,
                            const float* __restrict__ w1,
                            const float* __restrict__ w2,
                            const float* __restrict__ so_b,
                            const float* __restrict__ aw_b,
                            const float* __restrict__ qmask,
                            ushort* __restrict__ out,
                            float* __restrict__ bias_out,
                            float* __restrict__ cum_y,
                            float* __restrict__ cum_x) {
    int i = blockIdx.x * 256 + threadIdx.x;
    if (i < WTOT) {
        float v;
        int j = i;
        if (j < SOW_N) v = so_w[j];
        else if ((j -= SOW_N) < AWW_N) v = aw_w[j];
        else if ((j -= AWW_N) < VPW_N) v = vp_w[j];
        else if ((j -= VPW_N) < OPW_N) v = op_w[j];
        else if ((j -= OPW_N) < W1_N)  v = w1[j];
        else { j -= W1_N; v = w2[j]; }
        out[i] = f2bf(v);
        return;
    }
    int j = i - WTOT;
    if (j < 384) {   // pad bias to 384 with zeros (col-tile over-read safety)
        bias_out[j] = (j < 216) ? so_b[j] : (j < 324 ? aw_b[j - 216] : 0.f);
        return;
    }
    int t = j - 384;
    if (t < Bc * Wc) {
        int b = t / Wc, w = t % Wc;
        float run = 0.f;
        for (int h = 0; h < Hc; ++h) {
            run += (qmask[(b * Hc + h) * Wc + w] == 255.0f) ? 0.f : 1.f;
            cum_y[(b * Hc + h) * Wc + w] = run;
        }
    } else if (t < Bc * Wc + Bc * Hc) {
        int t2 = t - Bc * Wc;
        int b = t2 / Hc, h = t2 % Hc;
        float run = 0.f;
        for (int w = 0; w < Wc; ++w) {
            run += (qmask[(b * Hc + h) * Wc + w] == 255.0f) ? 0.f : 1.f;
            cum_x[(b * Hc + h) * Wc + w] = run;
        }
    }
}

// ---------------------------------------------------------------------------
// K1: transpose x[B,D,N] -> src_bf[B,N,D] (bf16);
//     qpos_bf = bf16(src + sine_pos + level_embed). Fast-math trig.
// ---------------------------------------------------------------------------
__global__ void transpose_pos_kernel(const float* __restrict__ x,
                                     const float* __restrict__ cum_y,
                                     const float* __restrict__ cum_x,
                                     const float* __restrict__ level_embed,
                                     ushort* __restrict__ src_bf,
                                     ushort* __restrict__ qpos_bf) {
    __shared__ float tile[32][33];
    int b  = blockIdx.z;
    int n0 = blockIdx.x * 32, d0 = blockIdx.y * 32;
    int tx = threadIdx.x, ty = threadIdx.y;
    tile[ty][tx] = x[((size_t)b * Dc + (d0 + ty)) * Nc + (n0 + tx)];
    __syncthreads();
    int n = n0 + ty, d = d0 + tx;
    float v = tile[tx][ty];
    size_t oi = ((size_t)b * Nc + n) * Dc + d;
    src_bf[oi] = f2bf(v);
    int h = n >> 6, w = n & 63;
    const float TWO_PI = 6.28318530717958647692f;
    float vy = cum_y[(b * Hc + h) * Wc + w] /
               (cum_y[(b * Hc + (Hc - 1)) * Wc + w] + 1e-6f) * TWO_PI;
    float vx = cum_x[(b * Hc + h) * Wc + w] /
               (cum_x[(b * Hc + h) * Wc + (Wc - 1)] + 1e-6f) * TWO_PI;
    int   i  = (d < 192) ? d : d - 192;
    float vv = (d < 192) ? vy : vx;
    float e   = (float)(i >> 1) * (2.0f / 192.0f);
    float idt = exp2f(e * -13.28771237954945f);
    float ang = vv * idt;
    float pe  = (i & 1) ? __cosf(ang) : __sinf(ang);
    qpos_bf[oi] = f2bf(v + pe + level_embed[d]);
}

// ---------------------------------------------------------------------------
// K2: bf16 MFMA GEMM core (R8-verified): m97-style 128x128 tile,
//     global_load_lds width=16, double-buffered LDS, one barrier/K-chunk,
//     blockIdx.x = row-stripe (fast-varying -> XCD L2 locality).
// ---------------------------------------------------------------------------
template <int KT>
__device__ __forceinline__ void gemm_core(
        const ushort* __restrict__ A, const ushort* __restrict__ Wt,
        const float* __restrict__ bias,
        float* __restrict__ Cf, ushort* __restrict__ Cb,
        int Nout, int relu, const float* __restrict__ qmask,
        ushort* As, ushort* Bs) {           // As/Bs: 2 x 128*32 each
    constexpr int NCH = KT / 32;
    const int tid  = threadIdx.x;
    const int m0   = blockIdx.x * 128;
    const int n0   = blockIdx.y * 128;
    const int lane = tid & 63;
    const int wv   = tid >> 6;
    const int wr   = (wv >> 1) * 64;
    const int wc   = (wv & 1) * 64;
    const int quad = lane >> 4;
    const int lrow = lane & 15;
    const int srow = wv * 32 + (lane >> 2);
    const int scol = (lane & 3) * 8;

    floatx4 acc[4][4];
    #pragma unroll
    for (int i = 0; i < 4; ++i)
        #pragma unroll
        for (int j = 0; j < 4; ++j)
            acc[i][j] = (floatx4)(0.f);

    #pragma unroll
    for (int s = 0; s < 2; ++s) {
        gload_lds16(A  + (size_t)(m0 + srow + s * 16) * KT + scol,
                    As + wv * 1024 + s * 512);
        gload_lds16(Wt + (size_t)(n0 + srow + s * 16) * KT + scol,
                    Bs + wv * 1024 + s * 512);
    }

    for (int c = 0; c < NCH; ++c) {
        const int cur = c & 1;
        __syncthreads();
        if (c + 1 < NCH) {
            const int k0 = (c + 1) * 32;
            #pragma unroll
            for (int s = 0; s < 2; ++s) {
                gload_lds16(A  + (size_t)(m0 + srow + s * 16) * KT + k0 + scol,
                            As + (cur ^ 1) * 4096 + wv * 1024 + s * 512);
                gload_lds16(Wt + (size_t)(n0 + srow + s * 16) * KT + k0 + scol,
                            Bs + (cur ^ 1) * 4096 + wv * 1024 + s * 512);
            }
        }
        short8 afr[4], bfr[4];
        #pragma unroll
        for (int i = 0; i < 4; ++i)
            afr[i] = *(const short8*)(As + cur * 4096 +
                                      (wr + i * 16 + lrow) * 32 + quad * 8);
        #pragma unroll
        for (int j = 0; j < 4; ++j)
            bfr[j] = *(const short8*)(Bs + cur * 4096 +
                                      (wc + j * 16 + lrow) * 32 + quad * 8);
        #pragma unroll
        for (int i = 0; i < 4; ++i)
            #pragma unroll
            for (int j = 0; j < 4; ++j)
                acc[i][j] = __builtin_amdgcn_mfma_f32_16x16x32_bf16(
                    afr[i], bfr[j], acc[i][j], 0, 0, 0);
    }

    float mz[4][4];
    #pragma unroll
    for (int i = 0; i < 4; ++i)
        #pragma unroll
        for (int r = 0; r < 4; ++r) {
            int row = m0 + wr + i * 16 + quad * 4 + r;
            mz[i][r] = (qmask && qmask[row] == 255.0f) ? 0.f : 1.f;
        }

    // C/D layout (16x16x32): col = lane&15, row = quad*4 + reg
    #pragma unroll
    for (int i = 0; i < 4; ++i) {
        #pragma unroll
        for (int j = 0; j < 4; ++j) {
            int col = n0 + wc + j * 16 + lrow;
            if (col >= Nout) continue;
            float bsv = bias ? bias[col] : 0.f;
            #pragma unroll
            for (int r = 0; r < 4; ++r) {
                int row = m0 + wr + i * 16 + quad * 4 + r;
                float v = acc[i][j][r] + bsv;
                if (relu) v = fmaxf(v, 0.f);
                v *= mz[i][r];
                if (Cf) Cf[(size_t)row * Nout + col] = v;
                if (Cb) Cb[(size_t)row * Nout + col] = f2bf(v);
            }
        }
    }
}

template <int KT>
__global__ __launch_bounds__(256) void gemm_single_kernel(
        const ushort* __restrict__ A, const ushort* __restrict__ Wt,
        const float* __restrict__ bias,
        float* __restrict__ Cf, ushort* __restrict__ Cb,
        int Nout, int relu, const float* __restrict__ qmask) {
    __shared__ ushort As[2 * 128 * 32];
    __shared__ ushort Bs[2 * 128 * 32];
    gemm_core<KT>(A, Wt, bias, Cf, Cb, Nout, relu, qmask, As, Bs);
}

// dual dispatch: z=0 -> soaw projection, z=1 -> value projection (overlapped)
__global__ __launch_bounds__(256) void gemm_dual_kernel(
        const ushort* __restrict__ A0, const ushort* __restrict__ W0,
        const float* __restrict__ b0, float* __restrict__ Cf0,
        const ushort* __restrict__ A1, const ushort* __restrict__ W1,
        const float* __restrict__ b1, ushort* __restrict__ Cb1,
        const float* __restrict__ qmask) {
    __shared__ ushort As[2 * 128 * 32];
    __shared__ ushort Bs[2 * 128 * 32];
    if (blockIdx.z == 0)
        gemm_core<384>(A0, W0, b0, Cf0, nullptr, 384, 0, nullptr, As, Bs);
    else
        gemm_core<384>(A1, W1, b1, nullptr, Cb1, 384, 0, qmask, As, Bs);
}

// ---------------------------------------------------------------------------
// K4: deformable attention gather (softmax fused, XCD-swizzled blocks).
//     4-lane group per (b,n,m); lane = 8 channels (bf16x8 = 16B loads).
//     soaw layout: [BN, 384] (216 offsets | 108 logits | 60 pad).
// ---------------------------------------------------------------------------
__global__ __launch_bounds__(256) void deform_attn_kernel(
        const ushort* __restrict__ value_bf, const float* __restrict__ soaw,
        ushort* __restrict__ out) {
    // swizzle: consecutive-n blocks land on the same XCD (bid%8 heuristic)
    int bid = blockIdx.x;                              // 0..3071
    int gb  = (bid & 7) * 384 + (bid >> 3);
    int gid = gb * 64 + (threadIdx.x >> 2);            // (b*N+n)*M + m
    int l4  = threadIdx.x & 3;                         // channel octet
    int m  = gid % Mc;
    int bn = gid / Mc;
    int b  = bn >> 12;
    int n  = bn & 4095;
    int h  = n >> 6, w = n & 63;
    const float* sop = soaw + (size_t)bn * 384 + m * 18;
    const float* lgt = soaw + (size_t)bn * 384 + 216 + m * Pc;
    float awv[Pc];
    float mx = lgt[0];
    #pragma unroll
    for (int i = 1; i < Pc; ++i) mx = fmaxf(mx, lgt[i]);
    float ssum = 0.f;
    #pragma unroll
    for (int i = 0; i < Pc; ++i) { awv[i] = __expf(lgt[i] - mx); ssum += awv[i]; }
    float sinv = 1.f / ssum;
    const ushort* vb = value_bf + ((size_t)b * Nc) * Dc + m * DHc + l4 * 8;
    float acc[8] = {0.f, 0.f, 0.f, 0.f, 0.f, 0.f, 0.f, 0.f};
    #pragma unroll
    for (int p = 0; p < Pc; ++p) {
        float2 so2 = *(const float2*)(sop + p * 2);
        float px = (float)w + so2.x;     // (ref + so/64)*64 - 0.5 simplifies
        float py = (float)h + so2.y;
        float x0f = floorf(px), y0f = floorf(py);
        float lx = px - x0f, ly = py - y0f;
        int x0 = (int)x0f, y0 = (int)y0f;
        int x1 = x0 + 1,  y1 = y0 + 1;
        float a = awv[p] * sinv;
        float w00 = (1.f - lx) * (1.f - ly) * a;
        float w01 = lx * (1.f - ly) * a;
        float w10 = (1.f - lx) * ly * a;
        float w11 = lx * ly * a;
        bool bx0 = (unsigned)x0 < 64u, bx1 = (unsigned)x1 < 64u;
        bool by0 = (unsigned)y0 < 64u, by1 = (unsigned)y1 < 64u;
        w00 = (bx0 && by0) ? w00 : 0.f;
        w01 = (bx1 && by0) ? w01 : 0.f;
        w10 = (bx0 && by1) ? w10 : 0.f;
        w11 = (bx1 && by1) ? w11 : 0.f;
        int cx0 = min(max(x0, 0), 63), cx1 = min(max(x1, 0), 63);
        int cy0 = min(max(y0, 0), 63), cy1 = min(max(y1, 0), 63);
        uint4 q00 = *(const uint4*)(vb + (size_t)(cy0 * 64 + cx0) * Dc);
        uint4 q01 = *(const uint4*)(vb + (size_t)(cy0 * 64 + cx1) * Dc);
        uint4 q10 = *(const uint4*)(vb + (size_t)(cy1 * 64 + cx0) * Dc);
        uint4 q11 = *(const uint4*)(vb + (size_t)(cy1 * 64 + cx1) * Dc);
        union { unsigned u; float f; } t;
        #define ACC2(word, wg, k)                                   \
            t.u = (word) << 16;         acc[k]     += (wg) * t.f;   \
            t.u = (word) & 0xffff0000u; acc[k + 1] += (wg) * t.f;
        #define ACC8(q, wg) \
            ACC2((q).x, wg, 0) ACC2((q).y, wg, 2) ACC2((q).z, wg, 4) ACC2((q).w, wg, 6)
        ACC8(q00, w00) ACC8(q01, w01) ACC8(q10, w10) ACC8(q11, w11)
        #undef ACC8
        #undef ACC2
    }
    short8 o;
    #pragma unroll
    for (int k = 0; k < 8; ++k) o[k] = (short)f2bf(acc[k]);
    *(short8*)(out + (size_t)bn * Dc + m * DHc + l4 * 8) = o;
}

// ---------------------------------------------------------------------------
// K5: q1 = LayerNorm(src_bf + proj_bf) -> q1_f (fp32) + q1_bf. bf16 inputs.
// ---------------------------------------------------------------------------
__global__ __launch_bounds__(128) void ln1_kernel(
        const ushort* __restrict__ a, const ushort* __restrict__ r,
        const float* __restrict__ g, const float* __restrict__ beta,
        float* __restrict__ outf, ushort* __restrict__ outb) {
    int row = blockIdx.x;
    int tid = threadIdx.x;
    float4 v = make_float4(0.f, 0.f, 0.f, 0.f);
    if (tid < 96) {
        ushort4 av = ((const ushort4*)(a + (size_t)row * Dc))[tid];
        ushort4 rv = ((const ushort4*)(r + (size_t)row * Dc))[tid];
        v.x = bf2f(av.x) + bf2f(rv.x); v.y = bf2f(av.y) + bf2f(rv.y);
        v.z = bf2f(av.z) + bf2f(rv.z); v.w = bf2f(av.w) + bf2f(rv.w);
    }
    float s1 = v.x + v.y + v.z + v.w;
    float s2 = v.x * v.x + v.y * v.y + v.z * v.z + v.w * v.w;
    __shared__ float sh1[128], sh2[128];
    sh1[tid] = s1; sh2[tid] = s2;
    __syncthreads();
    for (int off = 64; off > 0; off >>= 1) {
        if (tid < off) { sh1[tid] += sh1[tid + off]; sh2[tid] += sh2[tid + off]; }
        __syncthreads();
    }
    float mu  = sh1[0] * (1.0f / Dc);
    float var = sh2[0] * (1.0f / Dc) - mu * mu;
    float rs  = rsqrtf(var + 1e-5f);
    if (tid < 96) {
        float4 gv = ((const float4*)g)[tid];
        float4 bv = ((const float4*)beta)[tid];
        float4 o;
        o.x = (v.x - mu) * rs * gv.x + bv.x;
        o.y = (v.y - mu) * rs * gv.y + bv.y;
        o.z = (v.z - mu) * rs * gv.z + bv.z;
        o.w = (v.w - mu) * rs * gv.w + bv.w;
        ((float4*)(outf + (size_t)row * Dc))[tid] = o;
        ushort4 ob;
        ob.x = f2bf(o.x); ob.y = f2bf(o.y);
        ob.z = f2bf(o.z); ob.w = f2bf(o.w);
        ((ushort4*)(outb + (size_t)row * Dc))[tid] = ob;
    }
}

// ---------------------------------------------------------------------------
// K6: fused LN2 + transpose: out[b,d,n] = LN(q1_f + ffn2_bf)[b,n,d]
//     Block: 32 queries x 384 dims; LDS tile for coalesced transposed writes.
// ---------------------------------------------------------------------------
__global__ __launch_bounds__(256) void ln2_transpose_kernel(
        const float* __restrict__ q1, const ushort* __restrict__ r,
        const float* __restrict__ g, const float* __restrict__ beta,
        float* __restrict__ out) {
    __shared__ float tile[32 * 388];
    __shared__ float ps1[256], ps2[256];
    __shared__ float mu_[32], rs_[32];
    const int b  = blockIdx.y;
    const int n0 = blockIdx.x * 32;
    const int tid = threadIdx.x;
    const int rr  = tid >> 3;     // 0..31 query within tile
    const int s8  = tid & 7;      // 0..7 column-eighth
    const size_t row = (size_t)b * Nc + n0 + rr;
    float s1 = 0.f, s2 = 0.f;
    #pragma unroll
    for (int i = 0; i < 12; ++i) {
        int c = s8 * 48 + i * 4;
        float4  av = *(const float4*)(q1 + row * Dc + c);
        ushort4 rv = *(const ushort4*)(r + row * Dc + c);
        float4 t;
        t.x = av.x + bf2f(rv.x); t.y = av.y + bf2f(rv.y);
        t.z = av.z + bf2f(rv.z); t.w = av.w + bf2f(rv.w);
        *(float4*)&tile[rr * 388 + c] = t;
        s1 += t.x + t.y + t.z + t.w;
        s2 += t.x * t.x + t.y * t.y + t.z * t.z + t.w * t.w;
    }
    ps1[tid] = s1; ps2[tid] = s2;
    __syncthreads();
    if (tid < 32) {
        float a1 = 0.f, a2 = 0.f;
        #pragma unroll
        for (int k = 0; k < 8; ++k) { a1 += ps1[tid * 8 + k]; a2 += ps2[tid * 8 + k]; }
        float mu = a1 * (1.0f / Dc);
        float var = a2 * (1.0f / Dc) - mu * mu;
        mu_[tid] = mu;
        rs_[tid] = rsqrtf(var + 1e-5f);
    }
    __syncthreads();
    const int dg = tid >> 5;      // 0..7
    const int nn = tid & 31;      // 0..31
    float mu = mu_[nn], rs = rs_[nn];
    #pragma unroll
    for (int j = 0; j < 48; ++j) {
        int d = dg * 48 + j;
        float val = (tile[nn * 388 + d] - mu) * rs * g[d] + beta[d];
        out[((size_t)b * Dc + d) * Nc + n0 + nn] = val;
    }
}

// ---------------------------------------------------------------------------
extern "C" void kernel_launch(void* const* d_in, const int* in_sizes, int n_in,
                              void* d_out, int out_size, void* d_ws, size_t ws_size,
                              hipStream_t stream) {
    (void)in_sizes; (void)n_in; (void)out_size; (void)ws_size;
    const float* x      = (const float*)d_in[0];
    const float* qmask  = (const float*)d_in[1];
    const float* so_w   = (const float*)d_in[2];
    const float* so_b   = (const float*)d_in[3];
    const float* aw_w   = (const float*)d_in[4];
    const float* aw_b   = (const float*)d_in[5];
    const float* vp_w   = (const float*)d_in[6];
    const float* vp_b   = (const float*)d_in[7];
    const float* op_w   = (const float*)d_in[8];
    const float* op_b   = (const float*)d_in[9];
    const float* ln1_g  = (const float*)d_in[10];
    const float* ln1_b  = (const float*)d_in[11];
    const float* w1     = (const float*)d_in[12];
    const float* w2     = (const float*)d_in[13];
    const float* ln2_g  = (const float*)d_in[14];
    const float* ln2_b  = (const float*)d_in[15];
    const float* lvl    = (const float*)d_in[16];
    float* out = (float*)d_out;

    // Workspace (~116 MB):
    float*  ws       = (float*)d_ws;
    float*  q1_f     = ws;                          // 6291456 f (LN1 out, LN2 residual)
    ushort* src_bf   = (ushort*)(q1_f + 6291456);   // 6291456 us (vp input + LN1 residual)
    ushort* qpos_bf  = src_bf + 6291456;            // 6291456 us (qpos -> attn -> q1_bf)
    ushort* value_bf = qpos_bf + 6291456;           // 6291456 us
    ushort* proj_bf  = value_bf + 6291456;          // 6291456 us (op out; later ffn2 out)
    ushort* hbuf_bf  = proj_bf + 6291456;           // 18874368 us (FFN hidden)
    float*  soaw_f   = (float*)hbuf_bf;             // 6291456 f overlay (dead pre-FFN1)
    ushort* wbuf     = hbuf_bf + 18874368;          // 1304064 us
    float*  soaw_bias= (float*)(wbuf + 1304064);    // 384 f (padded)
    float*  cum_y    = soaw_bias + 384;             // 16384 f
    float*  cum_x    = cum_y + 16384;               // 16384 f

    const ushort* soaw_wb = wbuf;                   // [324,384] (so_w ++ aw_w)
    const ushort* vp_wb = soaw_wb + SOW_N + AWW_N;
    const ushort* op_wb = vp_wb + VPW_N;
    const ushort* w1_b  = op_wb + OPW_N;
    const ushort* w2_b  = w1_b + W1_N;

    // 0) fused init
    init_kernel<<<(WTOT + 384 + 512 + 255) / 256, 256, 0, stream>>>(
        so_w, aw_w, vp_w, op_w, w1, w2, so_b, aw_b, qmask,
        wbuf, soaw_bias, cum_y, cum_x);
    // 1) transpose + pos encode (bf16 outputs only)
    transpose_pos_kernel<<<dim3(Nc / 32, Dc / 32, Bc), dim3(32, 32), 0, stream>>>(
        x, cum_y, cum_x, lvl, src_bf, qpos_bf);
    // 2) DUAL: z=0 soaw projection (fp32 out), z=1 value projection (bf16+mask)
    gemm_dual_kernel<<<dim3(BNc / 128, 3, 2), 256, 0, stream>>>(
        qpos_bf, soaw_wb, soaw_bias, soaw_f,
        src_bf, vp_wb, vp_b, value_bf, qmask);
    // 3) deformable gather (softmax fused) -> attn into qpos_bf (qpos dead)
    deform_attn_kernel<<<(BNc * Mc) / 64, 256, 0, stream>>>(
        value_bf, soaw_f, qpos_bf);
    // 4) output projection -> proj_bf (bf16 only)
    gemm_single_kernel<384><<<dim3(BNc / 128, 3), 256, 0, stream>>>(
        qpos_bf, op_wb, op_b, nullptr, proj_bf, Dc, 0, nullptr);
    // 5) q1 = LN(src + attnproj): bf16 in -> q1_f + q1_bf (into qpos_bf)
    ln1_kernel<<<BNc, 128, 0, stream>>>(
        src_bf, proj_bf, ln1_g, ln1_b, q1_f, qpos_bf);
    // 6) FFN (hbuf overlays soaw — dead after gather)
    gemm_single_kernel<384><<<dim3(BNc / 128, 9), 256, 0, stream>>>(
        qpos_bf, w1_b, nullptr, nullptr, hbuf_bf, DFFc, 1, nullptr);
    gemm_single_kernel<1152><<<dim3(BNc / 128, 3), 256, 0, stream>>>(
        hbuf_bf, w2_b, nullptr, nullptr, proj_bf, Dc, 0, nullptr);
    // 7) fused q2 = LN(q1 + ffn2) + transpose to [B,D,H,W]
    ln2_transpose_kernel<<<dim3(Nc / 32, Bc), 256, 0, stream>>>(
        q1_f, proj_bf, ln2_g, ln2_b, out);
}

// Round 10
// 265.184 us; speedup vs baseline: 1.5626x; 1.0253x over previous
//
#include <hip/hip_runtime.h>
#include <math.h>

// Problem constants
#define Bc   4
#define Hc   64
#define Wc   64
#define Dc   384
#define Nc   4096      // H*W
#define Mc   12
#define Pc   9
#define DHc  32
#define DFFc 1152
#define BNc  (Bc*Nc)   // 16384

typedef __attribute__((ext_vector_type(8))) short short8;
typedef __attribute__((ext_vector_type(4))) float floatx4;

__device__ __forceinline__ ushort f2bf(float f) {
    union { float f; unsigned u; } v; v.f = f;
    unsigned r = v.u + 0x7fffu + ((v.u >> 16) & 1u);   // RNE
    return (ushort)(r >> 16);
}
__device__ __forceinline__ float bf2f(ushort u) {
    union { unsigned u; float f; } v; v.u = (unsigned)u << 16; return v.f;
}

__device__ __forceinline__ void gload_lds16(const void* g, void* l) {
    __builtin_amdgcn_global_load_lds(
        (const __attribute__((address_space(1))) void*)(uintptr_t)g,
        (__attribute__((address_space(3))) void*)(uintptr_t)l,
        16, 0, 0);
}

// ---------------------------------------------------------------------------
// K0: fused init — weight fp32->bf16 convert, bias concat, mask cumsums
// ---------------------------------------------------------------------------
#define SOW_N  82944     // 216*384
#define AWW_N  41472     // 108*384
#define VPW_N  147456    // 384*384
#define OPW_N  147456
#define W1_N   442368    // 1152*384
#define W2_N   442368    // 384*1152
#define WTOT   1304064

__global__ void init_kernel(const float* __restrict__ so_w,
                            const float* __restrict__ aw_w,
                            const float* __restrict__ vp_w,
                            const float* __restrict__ op_w,
                            const float* __restrict__ w1,
                            const float* __restrict__ w2,
                            const float* __restrict__ so_b,
                            const float* __restrict__ aw_b,
                            const float* __restrict__ qmask,
                            ushort* __restrict__ out,
                            float* __restrict__ bias_out,
                            float* __restrict__ cum_y,
                            float* __restrict__ cum_x) {
    int i = blockIdx.x * 256 + threadIdx.x;
    if (i < WTOT) {
        float v;
        int j = i;
        if (j < SOW_N) v = so_w[j];
        else if ((j -= SOW_N) < AWW_N) v = aw_w[j];
        else if ((j -= AWW_N) < VPW_N) v = vp_w[j];
        else if ((j -= VPW_N) < OPW_N) v = op_w[j];
        else if ((j -= OPW_N) < W1_N)  v = w1[j];
        else { j -= W1_N; v = w2[j]; }
        out[i] = f2bf(v);
        return;
    }
    int j = i - WTOT;
    if (j < 384) {   // pad bias to 384 with zeros (col-tile over-read safety)
        bias_out[j] = (j < 216) ? so_b[j] : (j < 324 ? aw_b[j - 216] : 0.f);
        return;
    }
    int t = j - 384;
    if (t < Bc * Wc) {
        int b = t / Wc, w = t % Wc;
        float run = 0.f;
        for (int h = 0; h < Hc; ++h) {
            run += (qmask[(b * Hc + h) * Wc + w] == 255.0f) ? 0.f : 1.f;
            cum_y[(b * Hc + h) * Wc + w] = run;
        }
    } else if (t < Bc * Wc + Bc * Hc) {
        int t2 = t - Bc * Wc;
        int b = t2 / Hc, h = t2 % Hc;
        float run = 0.f;
        for (int w = 0; w < Wc; ++w) {
            run += (qmask[(b * Hc + h) * Wc + w] == 255.0f) ? 0.f : 1.f;
            cum_x[(b * Hc + h) * Wc + w] = run;
        }
    }
}

// ---------------------------------------------------------------------------
// K1: transpose x[B,D,N] -> src_bf[B,N,D] (bf16);
//     qpos_bf = bf16(src + sine_pos + level_embed). Fast-math trig.
// ---------------------------------------------------------------------------
__global__ void transpose_pos_kernel(const float* __restrict__ x,
                                     const float* __restrict__ cum_y,
                                     const float* __restrict__ cum_x,
                                     const float* __restrict__ level_embed,
                                     ushort* __restrict__ src_bf,
                                     ushort* __restrict__ qpos_bf) {
    __shared__ float tile[32][33];
    int b  = blockIdx.z;
    int n0 = blockIdx.x * 32, d0 = blockIdx.y * 32;
    int tx = threadIdx.x, ty = threadIdx.y;
    tile[ty][tx] = x[((size_t)b * Dc + (d0 + ty)) * Nc + (n0 + tx)];
    __syncthreads();
    int n = n0 + ty, d = d0 + tx;
    float v = tile[tx][ty];
    size_t oi = ((size_t)b * Nc + n) * Dc + d;
    src_bf[oi] = f2bf(v);
    int h = n >> 6, w = n & 63;
    const float TWO_PI = 6.28318530717958647692f;
    float vy = cum_y[(b * Hc + h) * Wc + w] /
               (cum_y[(b * Hc + (Hc - 1)) * Wc + w] + 1e-6f) * TWO_PI;
    float vx = cum_x[(b * Hc + h) * Wc + w] /
               (cum_x[(b * Hc + h) * Wc + (Wc - 1)] + 1e-6f) * TWO_PI;
    int   i  = (d < 192) ? d : d - 192;
    float vv = (d < 192) ? vy : vx;
    float e   = (float)(i >> 1) * (2.0f / 192.0f);
    float idt = exp2f(e * -13.28771237954945f);
    float ang = vv * idt;
    float pe  = (i & 1) ? __cosf(ang) : __sinf(ang);
    qpos_bf[oi] = f2bf(v + pe + level_embed[d]);
}

// ---------------------------------------------------------------------------
// K2: bf16 MFMA GEMM core (R8/R9-verified): 128x128 tile, global_load_lds,
//     double-buffered LDS, one barrier/K-chunk, row-fast grid for XCD L2.
// ---------------------------------------------------------------------------
template <int KT>
__device__ __forceinline__ void gemm_core(
        const ushort* __restrict__ A, const ushort* __restrict__ Wt,
        const float* __restrict__ bias,
        float* __restrict__ Cf, ushort* __restrict__ Cb,
        int Nout, int relu, const float* __restrict__ qmask,
        ushort* As, ushort* Bs) {           // As/Bs: 2 x 128*32 each
    constexpr int NCH = KT / 32;
    const int tid  = threadIdx.x;
    const int m0   = blockIdx.x * 128;
    const int n0   = blockIdx.y * 128;
    const int lane = tid & 63;
    const int wv   = tid >> 6;
    const int wr   = (wv >> 1) * 64;
    const int wc   = (wv & 1) * 64;
    const int quad = lane >> 4;
    const int lrow = lane & 15;
    const int srow = wv * 32 + (lane >> 2);
    const int scol = (lane & 3) * 8;

    floatx4 acc[4][4];
    #pragma unroll
    for (int i = 0; i < 4; ++i)
        #pragma unroll
        for (int j = 0; j < 4; ++j)
            acc[i][j] = (floatx4)(0.f);

    #pragma unroll
    for (int s = 0; s < 2; ++s) {
        gload_lds16(A  + (size_t)(m0 + srow + s * 16) * KT + scol,
                    As + wv * 1024 + s * 512);
        gload_lds16(Wt + (size_t)(n0 + srow + s * 16) * KT + scol,
                    Bs + wv * 1024 + s * 512);
    }

    for (int c = 0; c < NCH; ++c) {
        const int cur = c & 1;
        __syncthreads();
        if (c + 1 < NCH) {
            const int k0 = (c + 1) * 32;
            #pragma unroll
            for (int s = 0; s < 2; ++s) {
                gload_lds16(A  + (size_t)(m0 + srow + s * 16) * KT + k0 + scol,
                            As + (cur ^ 1) * 4096 + wv * 1024 + s * 512);
                gload_lds16(Wt + (size_t)(n0 + srow + s * 16) * KT + k0 + scol,
                            Bs + (cur ^ 1) * 4096 + wv * 1024 + s * 512);
            }
        }
        short8 afr[4], bfr[4];
        #pragma unroll
        for (int i = 0; i < 4; ++i)
            afr[i] = *(const short8*)(As + cur * 4096 +
                                      (wr + i * 16 + lrow) * 32 + quad * 8);
        #pragma unroll
        for (int j = 0; j < 4; ++j)
            bfr[j] = *(const short8*)(Bs + cur * 4096 +
                                      (wc + j * 16 + lrow) * 32 + quad * 8);
        #pragma unroll
        for (int i = 0; i < 4; ++i)
            #pragma unroll
            for (int j = 0; j < 4; ++j)
                acc[i][j] = __builtin_amdgcn_mfma_f32_16x16x32_bf16(
                    afr[i], bfr[j], acc[i][j], 0, 0, 0);
    }

    float mz[4][4];
    #pragma unroll
    for (int i = 0; i < 4; ++i)
        #pragma unroll
        for (int r = 0; r < 4; ++r) {
            int row = m0 + wr + i * 16 + quad * 4 + r;
            mz[i][r] = (qmask && qmask[row] == 255.0f) ? 0.f : 1.f;
        }

    #pragma unroll
    for (int i = 0; i < 4; ++i) {
        #pragma unroll
        for (int j = 0; j < 4; ++j) {
            int col = n0 + wc + j * 16 + lrow;
            if (col >= Nout) continue;
            float bsv = bias ? bias[col] : 0.f;
            #pragma unroll
            for (int r = 0; r < 4; ++r) {
                int row = m0 + wr + i * 16 + quad * 4 + r;
                float v = acc[i][j][r] + bsv;
                if (relu) v = fmaxf(v, 0.f);
                v *= mz[i][r];
                if (Cf) Cf[(size_t)row * Nout + col] = v;
                if (Cb) Cb[(size_t)row * Nout + col] = f2bf(v);
            }
        }
    }
}

template <int KT>
__global__ __launch_bounds__(256) void gemm_single_kernel(
        const ushort* __restrict__ A, const ushort* __restrict__ Wt,
        const float* __restrict__ bias,
        float* __restrict__ Cf, ushort* __restrict__ Cb,
        int Nout, int relu, const float* __restrict__ qmask) {
    __shared__ ushort As[2 * 128 * 32];
    __shared__ ushort Bs[2 * 128 * 32];
    gemm_core<KT>(A, Wt, bias, Cf, Cb, Nout, relu, qmask, As, Bs);
}

// dual dispatch: z=0 -> soaw projection, z=1 -> value projection (overlapped)
__global__ __launch_bounds__(256) void gemm_dual_kernel(
        const ushort* __restrict__ A0, const ushort* __restrict__ W0,
        const float* __restrict__ b0, float* __restrict__ Cf0,
        const ushort* __restrict__ A1, const ushort* __restrict__ W1,
        const float* __restrict__ b1, ushort* __restrict__ Cb1,
        const float* __restrict__ qmask) {
    __shared__ ushort As[2 * 128 * 32];
    __shared__ ushort Bs[2 * 128 * 32];
    if (blockIdx.z == 0)
        gemm_core<384>(A0, W0, b0, Cf0, nullptr, 384, 0, nullptr, As, Bs);
    else
        gemm_core<384>(A1, W1, b1, nullptr, Cb1, 384, 0, qmask, As, Bs);
}

// ---------------------------------------------------------------------------
// K3: full-row GEMM + LayerNorm fusion.
//     Block: 512 threads (8 waves), 64-row stripe x ALL 384 cols. Grid = 256.
//     Wave wv covers cols [wv*48, wv*48+48) (3 j-tiles), rows 0..63 (4 i-tiles).
//     A (64x32/chunk) + B (384x32/chunk) double-buffered in LDS via
//     global_load_lds; per chunk: 12 MFMAs/wave, 1 barrier.
//     Epilogue: t = acc + bias + residual; row sums via shfl_xor(16) +
//     8-wave LDS combine -> LN.
//     MODE 0: residual bf16 (src), write q1_f (fp32) + q1_bf (bf16).
//     MODE 1: residual fp32 (q1), write transposed fp32 out[b,d,n] via
//             padded LDS tile (stride 193, conflict-free) in 2 col-halves.
// ---------------------------------------------------------------------------
template <int KT, int MODE>
__global__ __launch_bounds__(512) void gemm_fullrow_kernel(
        const ushort* __restrict__ A, const ushort* __restrict__ Wt,
        const float* __restrict__ bias, const void* __restrict__ resid,
        const float* __restrict__ g, const float* __restrict__ beta,
        float* __restrict__ outf, ushort* __restrict__ outb) {
    constexpr int NCH = KT / 32;
    __shared__ ushort smem[28672];            // 56KB: As 2x2K ush, Bs 2x12K ush
    __shared__ float eps1[8][64], eps2[8][64];
    __shared__ float mu_l[64], rs_l[64];
    ushort* As = smem;                        // bufs at cur*2048
    ushort* Bs = smem + 4096;                 // bufs at cur*12288
    const int tid  = threadIdx.x;
    const int lane = tid & 63;
    const int wv   = tid >> 6;                // 0..7
    const int quad = lane >> 4;
    const int lrow = lane & 15;
    const int m0   = blockIdx.x * 64;
    const int srow = lane >> 2;               // 0..15 within a 16-row group
    const int scol = (lane & 3) * 8;

    floatx4 acc[4][3];
    #pragma unroll
    for (int i = 0; i < 4; ++i)
        #pragma unroll
        for (int j = 0; j < 3; ++j)
            acc[i][j] = (floatx4)(0.f);

    // prologue: stage chunk 0 into buf 0
    if (wv < 4)
        gload_lds16(A + (size_t)(m0 + wv * 16 + srow) * KT + scol,
                    As + wv * 512);
    #pragma unroll
    for (int s = 0; s < 3; ++s)
        gload_lds16(Wt + (size_t)(wv * 48 + s * 16 + srow) * KT + scol,
                    Bs + wv * 1536 + s * 512);

    for (int c = 0; c < NCH; ++c) {
        const int cur = c & 1;
        __syncthreads();
        if (c + 1 < NCH) {
            const int k0 = (c + 1) * 32;
            if (wv < 4)
                gload_lds16(A + (size_t)(m0 + wv * 16 + srow) * KT + k0 + scol,
                            As + (cur ^ 1) * 2048 + wv * 512);
            #pragma unroll
            for (int s = 0; s < 3; ++s)
                gload_lds16(Wt + (size_t)(wv * 48 + s * 16 + srow) * KT + k0 + scol,
                            Bs + (cur ^ 1) * 12288 + wv * 1536 + s * 512);
        }
        short8 afr[4], bfr[3];
        #pragma unroll
        for (int i = 0; i < 4; ++i)
            afr[i] = *(const short8*)(As + cur * 2048 +
                                      (i * 16 + lrow) * 32 + quad * 8);
        #pragma unroll
        for (int j = 0; j < 3; ++j)
            bfr[j] = *(const short8*)(Bs + cur * 12288 +
                                      (wv * 48 + j * 16 + lrow) * 32 + quad * 8);
        #pragma unroll
        for (int i = 0; i < 4; ++i)
            #pragma unroll
            for (int j = 0; j < 3; ++j)
                acc[i][j] = __builtin_amdgcn_mfma_f32_16x16x32_bf16(
                    afr[i], bfr[j], acc[i][j], 0, 0, 0);
    }

    // --- epilogue: residual add + row-sum ---
    float s1[16], s2[16];
    #pragma unroll
    for (int k = 0; k < 16; ++k) { s1[k] = 0.f; s2[k] = 0.f; }
    #pragma unroll
    for (int i = 0; i < 4; ++i) {
        #pragma unroll
        for (int r = 0; r < 4; ++r) {
            int rl = i * 16 + quad * 4 + r;
            #pragma unroll
            for (int j = 0; j < 3; ++j) {
                int col = wv * 48 + j * 16 + lrow;
                float t = acc[i][j][r];
                if (bias) t += bias[col];
                if (MODE == 0)
                    t += bf2f(((const ushort*)resid)[(size_t)(m0 + rl) * Dc + col]);
                else
                    t += ((const float*)resid)[(size_t)(m0 + rl) * Dc + col];
                acc[i][j][r] = t;
                s1[i * 4 + r] += t;
                s2[i * 4 + r] += t * t;
            }
        }
    }
    // reduce over the 16 lrow lanes (bits 0..3 of lane id)
    #pragma unroll
    for (int m = 1; m < 16; m <<= 1) {
        #pragma unroll
        for (int k = 0; k < 16; ++k) {
            s1[k] += __shfl_xor(s1[k], m);
            s2[k] += __shfl_xor(s2[k], m);
        }
    }
    if (lrow == 0) {
        #pragma unroll
        for (int i = 0; i < 4; ++i)
            #pragma unroll
            for (int r = 0; r < 4; ++r) {
                int rl = i * 16 + quad * 4 + r;
                eps1[wv][rl] = s1[i * 4 + r];
                eps2[wv][rl] = s2[i * 4 + r];
            }
    }
    __syncthreads();
    if (tid < 64) {
        float a1 = 0.f, a2 = 0.f;
        #pragma unroll
        for (int w = 0; w < 8; ++w) { a1 += eps1[w][tid]; a2 += eps2[w][tid]; }
        float mu  = a1 * (1.0f / Dc);
        float var = a2 * (1.0f / Dc) - mu * mu;
        mu_l[tid] = mu;
        rs_l[tid] = rsqrtf(var + 1e-5f);
    }
    __syncthreads();

    // normalize in place
    #pragma unroll
    for (int i = 0; i < 4; ++i) {
        #pragma unroll
        for (int r = 0; r < 4; ++r) {
            int rl = i * 16 + quad * 4 + r;
            float mu = mu_l[rl], rs = rs_l[rl];
            #pragma unroll
            for (int j = 0; j < 3; ++j) {
                int col = wv * 48 + j * 16 + lrow;
                acc[i][j][r] = (acc[i][j][r] - mu) * rs * g[col] + beta[col];
            }
        }
    }

    if (MODE == 0) {
        #pragma unroll
        for (int i = 0; i < 4; ++i)
            #pragma unroll
            for (int j = 0; j < 3; ++j) {
                int col = wv * 48 + j * 16 + lrow;
                #pragma unroll
                for (int r = 0; r < 4; ++r) {
                    int rl = i * 16 + quad * 4 + r;
                    float v = acc[i][j][r];
                    outf[(size_t)(m0 + rl) * Dc + col] = v;
                    outb[(size_t)(m0 + rl) * Dc + col] = f2bf(v);
                }
            }
    } else {
        // transposed write via LDS tile (64 rows x 192 cols, stride 193)
        float* tile = (float*)smem;
        const int b   = m0 >> 12;
        const int n0r = m0 & 4095;
        #pragma unroll
        for (int gp = 0; gp < 2; ++gp) {
            __syncthreads();                  // tile free / prev pass done
            if ((wv >> 2) == gp) {
                int cbase = (wv & 3) * 48;
                #pragma unroll
                for (int i = 0; i < 4; ++i)
                    #pragma unroll
                    for (int j = 0; j < 3; ++j) {
                        int c = cbase + j * 16 + lrow;
                        #pragma unroll
                        for (int r = 0; r < 4; ++r) {
                            int rl = i * 16 + quad * 4 + r;
                            tile[rl * 193 + c] = acc[i][j][r];
                        }
                    }
            }
            __syncthreads();
            const int row = tid & 63;
            const int cp  = tid >> 6;         // 0..7
            #pragma unroll
            for (int it = 0; it < 24; ++it) {
                int c = it * 8 + cp;
                outf[((size_t)(b * Dc + gp * 192 + c)) * Nc + n0r + row] =
                    tile[row * 193 + c];
            }
        }
    }
}

// ---------------------------------------------------------------------------
// K4: deformable attention gather (softmax fused, XCD-swizzled blocks).
// ---------------------------------------------------------------------------
__global__ __launch_bounds__(256) void deform_attn_kernel(
        const ushort* __restrict__ value_bf, const float* __restrict__ soaw,
        ushort* __restrict__ out) {
    int bid = blockIdx.x;                              // 0..3071
    int gb  = (bid & 7) * 384 + (bid >> 3);
    int gid = gb * 64 + (threadIdx.x >> 2);            // (b*N+n)*M + m
    int l4  = threadIdx.x & 3;                         // channel octet
    int m  = gid % Mc;
    int bn = gid / Mc;
    int b  = bn >> 12;
    int n  = bn & 4095;
    int h  = n >> 6, w = n & 63;
    const float* sop = soaw + (size_t)bn * 384 + m * 18;
    const float* lgt = soaw + (size_t)bn * 384 + 216 + m * Pc;
    float awv[Pc];
    float mx = lgt[0];
    #pragma unroll
    for (int i = 1; i < Pc; ++i) mx = fmaxf(mx, lgt[i]);
    float ssum = 0.f;
    #pragma unroll
    for (int i = 0; i < Pc; ++i) { awv[i] = __expf(lgt[i] - mx); ssum += awv[i]; }
    float sinv = 1.f / ssum;
    const ushort* vb = value_bf + ((size_t)b * Nc) * Dc + m * DHc + l4 * 8;
    float acc[8] = {0.f, 0.f, 0.f, 0.f, 0.f, 0.f, 0.f, 0.f};
    #pragma unroll
    for (int p = 0; p < Pc; ++p) {
        float2 so2 = *(const float2*)(sop + p * 2);
        float px = (float)w + so2.x;
        float py = (float)h + so2.y;
        float x0f = floorf(px), y0f = floorf(py);
        float lx = px - x0f, ly = py - y0f;
        int x0 = (int)x0f, y0 = (int)y0f;
        int x1 = x0 + 1,  y1 = y0 + 1;
        float a = awv[p] * sinv;
        float w00 = (1.f - lx) * (1.f - ly) * a;
        float w01 = lx * (1.f - ly) * a;
        float w10 = (1.f - lx) * ly * a;
        float w11 = lx * ly * a;
        bool bx0 = (unsigned)x0 < 64u, bx1 = (unsigned)x1 < 64u;
        bool by0 = (unsigned)y0 < 64u, by1 = (unsigned)y1 < 64u;
        w00 = (bx0 && by0) ? w00 : 0.f;
        w01 = (bx1 && by0) ? w01 : 0.f;
        w10 = (bx0 && by1) ? w10 : 0.f;
        w11 = (bx1 && by1) ? w11 : 0.f;
        int cx0 = min(max(x0, 0), 63), cx1 = min(max(x1, 0), 63);
        int cy0 = min(max(y0, 0), 63), cy1 = min(max(y1, 0), 63);
        uint4 q00 = *(const uint4*)(vb + (size_t)(cy0 * 64 + cx0) * Dc);
        uint4 q01 = *(const uint4*)(vb + (size_t)(cy0 * 64 + cx1) * Dc);
        uint4 q10 = *(const uint4*)(vb + (size_t)(cy1 * 64 + cx0) * Dc);
        uint4 q11 = *(const uint4*)(vb + (size_t)(cy1 * 64 + cx1) * Dc);
        union { unsigned u; float f; } t;
        #define ACC2(word, wg, k)                                   \
            t.u = (word) << 16;         acc[k]     += (wg) * t.f;   \
            t.u = (word) & 0xffff0000u; acc[k + 1] += (wg) * t.f;
        #define ACC8(q, wg) \
            ACC2((q).x, wg, 0) ACC2((q).y, wg, 2) ACC2((q).z, wg, 4) ACC2((q).w, wg, 6)
        ACC8(q00, w00) ACC8(q01, w01) ACC8(q10, w10) ACC8(q11, w11)
        #undef ACC8
        #undef ACC2
    }
    short8 o;
    #pragma unroll
    for (int k = 0; k < 8; ++k) o[k] = (short)f2bf(acc[k]);
    *(short8*)(out + (size_t)bn * Dc + m * DHc + l4 * 8) = o;
}

// ---------------------------------------------------------------------------
extern "C" void kernel_launch(void* const* d_in, const int* in_sizes, int n_in,
                              void* d_out, int out_size, void* d_ws, size_t ws_size,
                              hipStream_t stream) {
    (void)in_sizes; (void)n_in; (void)out_size; (void)ws_size;
    const float* x      = (const float*)d_in[0];
    const float* qmask  = (const float*)d_in[1];
    const float* so_w   = (const float*)d_in[2];
    const float* so_b   = (const float*)d_in[3];
    const float* aw_w   = (const float*)d_in[4];
    const float* aw_b   = (const float*)d_in[5];
    const float* vp_w   = (const float*)d_in[6];
    const float* vp_b   = (const float*)d_in[7];
    const float* op_w   = (const float*)d_in[8];
    const float* op_b   = (const float*)d_in[9];
    const float* ln1_g  = (const float*)d_in[10];
    const float* ln1_b  = (const float*)d_in[11];
    const float* w1     = (const float*)d_in[12];
    const float* w2     = (const float*)d_in[13];
    const float* ln2_g  = (const float*)d_in[14];
    const float* ln2_b  = (const float*)d_in[15];
    const float* lvl    = (const float*)d_in[16];
    float* out = (float*)d_out;

    // Workspace (~104 MB):
    float*  ws       = (float*)d_ws;
    float*  q1_f     = ws;                          // 6291456 f (LN1 out / LN2 residual)
    ushort* src_bf   = (ushort*)(q1_f + 6291456);   // 6291456 us
    ushort* qpos_bf  = src_bf + 6291456;            // 6291456 us (qpos->attn->q1_bf)
    ushort* value_bf = qpos_bf + 6291456;           // 6291456 us
    ushort* hbuf_bf  = value_bf + 6291456;          // 18874368 us (FFN hidden)
    float*  soaw_f   = (float*)hbuf_bf;             // 6291456 f overlay (dead pre-FFN1)
    ushort* wbuf     = hbuf_bf + 18874368;          // 1304064 us
    float*  soaw_bias= (float*)(wbuf + 1304064);    // 384 f (padded)
    float*  cum_y    = soaw_bias + 384;             // 16384 f
    float*  cum_x    = cum_y + 16384;               // 16384 f

    const ushort* soaw_wb = wbuf;                   // [324,384] (so_w ++ aw_w)
    const ushort* vp_wb = soaw_wb + SOW_N + AWW_N;
    const ushort* op_wb = vp_wb + VPW_N;
    const ushort* w1_b  = op_wb + OPW_N;
    const ushort* w2_b  = w1_b + W1_N;

    // 0) fused init
    init_kernel<<<(WTOT + 384 + 512 + 255) / 256, 256, 0, stream>>>(
        so_w, aw_w, vp_w, op_w, w1, w2, so_b, aw_b, qmask,
        wbuf, soaw_bias, cum_y, cum_x);
    // 1) transpose + pos encode
    transpose_pos_kernel<<<dim3(Nc / 32, Dc / 32, Bc), dim3(32, 32), 0, stream>>>(
        x, cum_y, cum_x, lvl, src_bf, qpos_bf);
    // 2) DUAL: z=0 soaw projection (fp32 out), z=1 value projection (bf16+mask)
    gemm_dual_kernel<<<dim3(BNc / 128, 3, 2), 256, 0, stream>>>(
        qpos_bf, soaw_wb, soaw_bias, soaw_f,
        src_bf, vp_wb, vp_b, value_bf, qmask);
    // 3) deformable gather (softmax fused) -> attn into qpos_bf (qpos dead)
    deform_attn_kernel<<<(BNc * Mc) / 64, 256, 0, stream>>>(
        value_bf, soaw_f, qpos_bf);
    // 4) fused op-proj + residual(src_bf) + LN1 -> q1_f + q1_bf (in qpos_bf)
    gemm_fullrow_kernel<384, 0><<<BNc / 64, 512, 0, stream>>>(
        qpos_bf, op_wb, op_b, src_bf, ln1_g, ln1_b, q1_f, qpos_bf);
    // 5) FFN1 (relu, bf16 hidden)
    gemm_single_kernel<384><<<dim3(BNc / 128, 9), 256, 0, stream>>>(
        qpos_bf, w1_b, nullptr, nullptr, hbuf_bf, DFFc, 1, nullptr);
    // 6) fused FFN2 + residual(q1_f) + LN2 + transpose -> out[B,D,N]
    gemm_fullrow_kernel<1152, 1><<<BNc / 64, 512, 0, stream>>>(
        hbuf_bf, w2_b, nullptr, q1_f, ln2_g, ln2_b, out, nullptr);
}